// Round 2
// baseline (1282.156 us; speedup 1.0000x reference)
//
#include <hip/hip_runtime.h>
#include <math.h>

#define TB 1024
#define HID 256

__device__ __forceinline__ float sigm(float x) { return 1.f / (1.f + expf(-x)); }

// ---------------- conv1: (1024,3,84,84) -> (1024,32,20,20), k8 s4, relu, x/255 folded ----------------
// One thread computes ALL 32 output channels for one output pixel: input loaded once per thread.
__global__ __launch_bounds__(256) void k_conv1(const float* __restrict__ img,
                                               const float* __restrict__ W,
                                               const float* __restrict__ B,
                                               float* __restrict__ out) {
    int g = blockIdx.x * 256 + threadIdx.x;      // 0..409599
    int im = g / 400;
    int pix = g - im * 400;
    int oy = pix / 20, ox = pix - (pix / 20) * 20;
    float acc[32];
#pragma unroll
    for (int i = 0; i < 32; ++i) acc[i] = 0.f;
    const float* ibase = img + im * (3 * 84 * 84);
#pragma unroll
    for (int c = 0; c < 3; ++c) {
#pragma unroll
        for (int ky = 0; ky < 8; ++ky) {
            const float* row = ibase + (c * 84 + oy * 4 + ky) * 84 + ox * 4;
            float4 v0 = *(const float4*)(row);
            float4 v1 = *(const float4*)(row + 4);
            float in[8] = {v0.x, v0.y, v0.z, v0.w, v1.x, v1.y, v1.z, v1.w};
#pragma unroll
            for (int kx = 0; kx < 8; ++kx) {
#pragma unroll
                for (int co = 0; co < 32; ++co)
                    acc[co] += in[kx] * W[(co * 3 + c) * 64 + ky * 8 + kx];
            }
        }
    }
    const float s = 1.f / 255.f;
#pragma unroll
    for (int co = 0; co < 32; ++co) {
        float v = acc[co] * s + B[co];
        out[((im * 32 + co) * 20 + oy) * 20 + ox] = v > 0.f ? v : 0.f;
    }
}

// ---------------- conv2: (1024,32,20,20) -> (1024,64,9,9), k4 s2, relu ----------------
// 16 output channels per thread (grid.y = 4).
__global__ __launch_bounds__(256) void k_conv2(const float* __restrict__ in,
                                               const float* __restrict__ W,
                                               const float* __restrict__ B,
                                               float* __restrict__ out) {
    int g = blockIdx.x * 256 + threadIdx.x;      // 0..82943
    int im = g / 81;
    int pix = g - im * 81;
    int oy = pix / 9, ox = pix - (pix / 9) * 9;
    int cog = blockIdx.y * 16;
    float acc[16];
#pragma unroll
    for (int i = 0; i < 16; ++i) acc[i] = 0.f;
    const float* ibase = in + im * 12800;
    for (int ci = 0; ci < 32; ++ci) {
#pragma unroll
        for (int ky = 0; ky < 4; ++ky) {
            const float* row = ibase + (ci * 20 + oy * 2 + ky) * 20 + ox * 2;
            float2 v0 = *(const float2*)(row);
            float2 v1 = *(const float2*)(row + 2);
            float inv[4] = {v0.x, v0.y, v1.x, v1.y};
#pragma unroll
            for (int kx = 0; kx < 4; ++kx) {
#pragma unroll
                for (int co = 0; co < 16; ++co)
                    acc[co] += inv[kx] * W[(((cog + co) * 32 + ci) * 4 + ky) * 4 + kx];
            }
        }
    }
#pragma unroll
    for (int co = 0; co < 16; ++co) {
        float v = acc[co] + B[cog + co];
        out[((im * 64 + cog + co) * 9 + oy) * 9 + ox] = v > 0.f ? v : 0.f;
    }
}

// ---------------- conv3: (1024,64,9,9) -> (1024,64,7,7) flat, k3 s1, relu ----------------
// 16 output channels per thread (grid.y = 4).
__global__ __launch_bounds__(256) void k_conv3(const float* __restrict__ in,
                                               const float* __restrict__ W,
                                               const float* __restrict__ B,
                                               float* __restrict__ out) {
    int g = blockIdx.x * 256 + threadIdx.x;      // 0..50175
    int im = g / 49;
    int pix = g - im * 49;
    int oy = pix / 7, ox = pix - (pix / 7) * 7;
    int cog = blockIdx.y * 16;
    float acc[16];
#pragma unroll
    for (int i = 0; i < 16; ++i) acc[i] = 0.f;
    const float* ibase = in + im * 5184;
    for (int ci = 0; ci < 64; ++ci) {
#pragma unroll
        for (int ky = 0; ky < 3; ++ky) {
            const float* row = ibase + (ci * 81) + (oy + ky) * 9 + ox;
            float inv[3] = {row[0], row[1], row[2]};
#pragma unroll
            for (int kx = 0; kx < 3; ++kx) {
#pragma unroll
                for (int co = 0; co < 16; ++co)
                    acc[co] += inv[kx] * W[(((cog + co) * 64 + ci) * 3 + ky) * 3 + kx];
            }
        }
    }
#pragma unroll
    for (int co = 0; co < 16; ++co) {
        float v = acc[co] + B[cog + co];
        // flatten layout: ch*49 + pix
        out[im * 3136 + (cog + co) * 49 + pix] = v > 0.f ? v : 0.f;
    }
}

// ---------------- FC: feat = relu(a3[1024,3136] @ Wfc^T[3136,512] + bfc) ----------------
__global__ __launch_bounds__(256) void k_fc(const float* __restrict__ X,
                                            const float* __restrict__ W,
                                            const float* __restrict__ B,
                                            float* __restrict__ out) {
    int lane = threadIdx.x & 63;
    int wv = threadIdx.x >> 6;
    int m0 = blockIdx.x * 8;
    int n0 = blockIdx.y * 32 + wv * 8;
    float acc[64];
#pragma unroll
    for (int i = 0; i < 64; ++i) acc[i] = 0.f;
    for (int kk = 0; kk < 49; ++kk) {
        int k = kk * 64 + lane;
        float xv[8], wvv[8];
#pragma unroll
        for (int i = 0; i < 8; ++i) xv[i] = X[(m0 + i) * 3136 + k];
#pragma unroll
        for (int i = 0; i < 8; ++i) wvv[i] = W[(n0 + i) * 3136 + k];
#pragma unroll
        for (int mi = 0; mi < 8; ++mi)
#pragma unroll
            for (int ni = 0; ni < 8; ++ni)
                acc[mi * 8 + ni] += xv[mi] * wvv[ni];
    }
    float r = 0.f;
#pragma unroll
    for (int i = 0; i < 64; ++i) {
        float s = acc[i];
        s += __shfl_xor(s, 1); s += __shfl_xor(s, 2); s += __shfl_xor(s, 4);
        s += __shfl_xor(s, 8); s += __shfl_xor(s, 16); s += __shfl_xor(s, 32);
        if (lane == i) r = s;
    }
    int mi = lane >> 3, ni = lane & 7;
    float v = r + B[n0 + ni];
    out[(m0 + mi) * 512 + (n0 + ni)] = v > 0.f ? v : 0.f;
}

// ---------------- gx = feat @ W_ih[:, :512]^T + W_ih[:,512+act] + b_ih + b_hh ----------------
__global__ __launch_bounds__(256) void k_gx(const float* __restrict__ X,   // feat 1024x512
                                            const float* __restrict__ Wih, // 1024x517
                                            const float* __restrict__ bih,
                                            const float* __restrict__ bhh,
                                            const int* __restrict__ act,
                                            float* __restrict__ out) {
    int lane = threadIdx.x & 63;
    int wv = threadIdx.x >> 6;
    int m0 = blockIdx.x * 8;
    int n0 = blockIdx.y * 32 + wv * 8;
    float acc[64];
#pragma unroll
    for (int i = 0; i < 64; ++i) acc[i] = 0.f;
    for (int kk = 0; kk < 8; ++kk) {
        int k = kk * 64 + lane;
        float xv[8], wvv[8];
#pragma unroll
        for (int i = 0; i < 8; ++i) xv[i] = X[(m0 + i) * 512 + k];
#pragma unroll
        for (int i = 0; i < 8; ++i) wvv[i] = Wih[(n0 + i) * 517 + k];
#pragma unroll
        for (int mi = 0; mi < 8; ++mi)
#pragma unroll
            for (int ni = 0; ni < 8; ++ni)
                acc[mi * 8 + ni] += xv[mi] * wvv[ni];
    }
    float r = 0.f;
#pragma unroll
    for (int i = 0; i < 64; ++i) {
        float s = acc[i];
        s += __shfl_xor(s, 1); s += __shfl_xor(s, 2); s += __shfl_xor(s, 4);
        s += __shfl_xor(s, 8); s += __shfl_xor(s, 16); s += __shfl_xor(s, 32);
        if (lane == i) r = s;
    }
    int mi = lane >> 3, ni = lane & 7;
    int m = m0 + mi, n = n0 + ni;
    int a = act[m];
    float v = r + Wih[n * 517 + 512 + a] + bih[n] + bhh[n];
    out[m * 1024 + n] = v;
}

// ---------------- one LSTM step: g = gx[t] + (h*mask) @ Whh^T ; gates ; write c,h ----------------
__global__ __launch_bounds__(256) void k_lstm_step(int t,
                                                   const float* __restrict__ hsrc,
                                                   const float* __restrict__ csrc,
                                                   float* __restrict__ cdst,
                                                   const float* __restrict__ gx,
                                                   const float* __restrict__ Whh, // 1024x256
                                                   const float* __restrict__ done,
                                                   float* __restrict__ hs) {
    int lane = threadIdx.x & 63;
    int Wv = (blockIdx.x * 256 + threadIdx.x) >> 6;   // 0..2047
    int bp = Wv >> 7;                                  // 0..15
    int np = Wv & 127;                                 // 0..127
    int b0 = bp * 2, n0 = np * 2;
    float mb0 = 1.f - done[t * 32 + b0];
    float mb1 = 1.f - done[t * 32 + b0 + 1];
    float acc[16];
#pragma unroll
    for (int i = 0; i < 16; ++i) acc[i] = 0.f;
#pragma unroll
    for (int it = 0; it < 4; ++it) {
        int k = it * 64 + lane;
        float h0v = hsrc[b0 * 256 + k] * mb0;
        float h1v = hsrc[(b0 + 1) * 256 + k] * mb1;
#pragma unroll
        for (int p = 0; p < 2; ++p) {
#pragma unroll
            for (int g2 = 0; g2 < 4; ++g2) {
                float wv = Whh[(g2 * 256 + n0 + p) * 256 + k];
                acc[(0 * 2 + p) * 4 + g2] += h0v * wv;
                acc[(1 * 2 + p) * 4 + g2] += h1v * wv;
            }
        }
    }
    float gate[4] = {0.f, 0.f, 0.f, 0.f};
#pragma unroll
    for (int bi = 0; bi < 2; ++bi) {
#pragma unroll
        for (int p = 0; p < 2; ++p) {
#pragma unroll
            for (int g2 = 0; g2 < 4; ++g2) {
                float s = acc[(bi * 2 + p) * 4 + g2];
                s += __shfl_xor(s, 1); s += __shfl_xor(s, 2); s += __shfl_xor(s, 4);
                s += __shfl_xor(s, 8); s += __shfl_xor(s, 16); s += __shfl_xor(s, 32);
                if ((lane & 3) == bi * 2 + p) gate[g2] = s;
            }
        }
    }
    if (lane < 4) {
        int bi = lane >> 1, p = lane & 1;
        int b = b0 + bi, n = n0 + p;
        int row = t * 32 + b;
        float gi = gate[0] + gx[row * 1024 + 0 * 256 + n];
        float gf = gate[1] + gx[row * 1024 + 1 * 256 + n];
        float gg = gate[2] + gx[row * 1024 + 2 * 256 + n];
        float go = gate[3] + gx[row * 1024 + 3 * 256 + n];
        float mb = bi ? mb1 : mb0;
        float cm = csrc[b * 256 + n] * mb;
        float cn = sigm(gf) * cm + sigm(gi) * tanhf(gg);
        float hn = sigm(go) * tanhf(cn);
        cdst[b * 256 + n] = cn;
        hs[t * 8192 + b * 256 + n] = hn;
    }
}

// ---------------- heads: logits = tanh(h@Wp1^T+bp1)@Wp2^T+bp2 ; v similarly ; copy hT,cT ----------------
__global__ __launch_bounds__(256) void k_heads(const float* __restrict__ hs,
                                               const float* __restrict__ cb,
                                               const float* __restrict__ Wp1, const float* __restrict__ bp1,
                                               const float* __restrict__ Wp2, const float* __restrict__ bp2,
                                               const float* __restrict__ Wv1, const float* __restrict__ bv1,
                                               const float* __restrict__ Wv2, const float* __restrict__ bv2,
                                               float* __restrict__ out) {
    int lane = threadIdx.x & 63;
    int m = blockIdx.x * 4 + (threadIdx.x >> 6);   // 0..1023
    const float4* hv = (const float4*)(hs + m * 256);
    const float4* wp = (const float4*)(Wp1 + lane * 256);
    const float4* wq = (const float4*)(Wv1 + lane * 256);
    float ap = 0.f, av = 0.f;
#pragma unroll 8
    for (int k = 0; k < 64; ++k) {
        float4 h4 = hv[k];
        float4 p4 = wp[k];
        float4 q4 = wq[k];
        ap += h4.x * p4.x + h4.y * p4.y + h4.z * p4.z + h4.w * p4.w;
        av += h4.x * q4.x + h4.y * q4.y + h4.z * q4.z + h4.w * q4.w;
    }
    float hp = tanhf(ap + bp1[lane]);
    float hq = tanhf(av + bv1[lane]);
#pragma unroll
    for (int j = 0; j < 5; ++j) {
        float s = hp * Wp2[j * 64 + lane];
        s += __shfl_xor(s, 1); s += __shfl_xor(s, 2); s += __shfl_xor(s, 4);
        s += __shfl_xor(s, 8); s += __shfl_xor(s, 16); s += __shfl_xor(s, 32);
        if (lane == 0) out[m * 5 + j] = s + bp2[j];
    }
    float s = hq * Wv2[lane];
    s += __shfl_xor(s, 1); s += __shfl_xor(s, 2); s += __shfl_xor(s, 4);
    s += __shfl_xor(s, 8); s += __shfl_xor(s, 16); s += __shfl_xor(s, 32);
    if (lane == 0) out[5120 + m] = s + bv2[0];

    int g = blockIdx.x * 256 + threadIdx.x;
    if (g < 8192) {
        out[6144 + g] = hs[31 * 8192 + g];          // hT
        out[6144 + 8192 + g] = cb[g];               // cT
    }
}

extern "C" void kernel_launch(void* const* d_in, const int* in_sizes, int n_in,
                              void* d_out, int out_size, void* d_ws, size_t ws_size,
                              hipStream_t stream) {
    const float* image = (const float*)d_in[0];
    const int*   act   = (const int*)d_in[1];
    const float* done  = (const float*)d_in[2];
    const float* h0    = (const float*)d_in[3];
    const float* c0    = (const float*)d_in[4];
    const float* W1    = (const float*)d_in[5];
    const float* b1    = (const float*)d_in[6];
    const float* W2    = (const float*)d_in[7];
    const float* b2    = (const float*)d_in[8];
    const float* W3    = (const float*)d_in[9];
    const float* b3    = (const float*)d_in[10];
    const float* Wfc   = (const float*)d_in[11];
    const float* bfc   = (const float*)d_in[12];
    const float* Wih   = (const float*)d_in[13];
    const float* Whh   = (const float*)d_in[14];
    const float* bih   = (const float*)d_in[15];
    const float* bhh   = (const float*)d_in[16];
    const float* Wp1   = (const float*)d_in[17];
    const float* bp1   = (const float*)d_in[18];
    const float* Wp2   = (const float*)d_in[19];
    const float* bp2   = (const float*)d_in[20];
    const float* Wv1   = (const float*)d_in[21];
    const float* bv1   = (const float*)d_in[22];
    const float* Wv2   = (const float*)d_in[23];
    const float* bv2   = (const float*)d_in[24];
    float* out = (float*)d_out;
    float* ws = (float*)d_ws;

    // workspace layout (floats); a3/feat/gx/hs/c_buf overlap dead a1
    float* a2   = ws;                    // 5,308,416
    float* a1   = ws + 5308416;          // 13,107,200
    float* a3   = ws + 5308416;          // 3,211,264 (reuses a1 after conv2)
    float* feat = ws + 8519680;          // 524,288
    float* gx   = ws + 9043968;          // 1,048,576
    float* hs   = ws + 10092544;         // 262,144
    float* cb   = ws + 10354688;         // 8,192

    k_conv1<<<dim3(1600, 1), 256, 0, stream>>>(image, W1, b1, a1);
    k_conv2<<<dim3(324, 4), 256, 0, stream>>>(a1, W2, b2, a2);
    k_conv3<<<dim3(196, 4), 256, 0, stream>>>(a2, W3, b3, a3);
    k_fc<<<dim3(128, 16), 256, 0, stream>>>(a3, Wfc, bfc, feat);
    k_gx<<<dim3(128, 32), 256, 0, stream>>>(feat, Wih, bih, bhh, act, gx);
    for (int t = 0; t < 32; ++t) {
        const float* hsrc = (t == 0) ? h0 : (hs + (t - 1) * 8192);
        const float* csrc = (t == 0) ? c0 : cb;
        k_lstm_step<<<512, 256, 0, stream>>>(t, hsrc, csrc, cb, gx, Whh, done, hs);
    }
    k_heads<<<256, 256, 0, stream>>>(hs, cb, Wp1, bp1, Wp2, bp2, Wv1, bv1, Wv2, bv2, out);
}

// Round 3
// 791.902 us; speedup vs baseline: 1.6191x; 1.6191x over previous
//
#include <hip/hip_runtime.h>
#include <math.h>

#define TB 1024
#define HID 256

__device__ __forceinline__ float sigm(float x) { return 1.f / (1.f + expf(-x)); }

// ---------------- conv1: (1024,3,84,84) -> (1024,32,20,20), k8 s4, relu, x/255 folded ----------------
// Weights repacked to LDS [c][ky][kx][co16]; thread = 2 adjacent pixels x 16 channels; grid.y = channel group (2).
__global__ __launch_bounds__(256) void k_conv1(const float* __restrict__ img,
                                               const float* __restrict__ W,
                                               const float* __restrict__ B,
                                               float* __restrict__ out) {
    __shared__ __align__(16) float w_lds[3072];          // 12 KB
    int cg = blockIdx.y;                                  // 0..1
#pragma unroll
    for (int l = threadIdx.x; l < 3072; l += 256) {
        int co = l & 15, r = l >> 4;                      // r = c*64 + ky*8 + kx
        w_lds[l] = W[((cg * 16 + co) * 3 + (r >> 6)) * 64 + (r & 63)];
    }
    __syncthreads();
    int g = blockIdx.x * 256 + threadIdx.x;               // 0..204799
    int im = g / 200;
    int pr = g - im * 200;                                // pair index 0..199
    int oy = pr / 10, ox0 = (pr - oy * 10) * 2;
    float acc[2][16];
#pragma unroll
    for (int p = 0; p < 2; ++p)
#pragma unroll
        for (int i = 0; i < 16; ++i) acc[p][i] = 0.f;
    const float* ibase = img + im * 21168;
#pragma unroll
    for (int c = 0; c < 3; ++c) {
#pragma unroll
        for (int ky = 0; ky < 8; ++ky) {
            const float* row = ibase + (c * 84 + oy * 4 + ky) * 84 + ox0 * 4;
            float4 v0 = *(const float4*)(row);
            float4 v1 = *(const float4*)(row + 4);
            float4 v2 = *(const float4*)(row + 8);
            float in[12] = {v0.x, v0.y, v0.z, v0.w, v1.x, v1.y, v1.z, v1.w, v2.x, v2.y, v2.z, v2.w};
#pragma unroll
            for (int kx = 0; kx < 8; ++kx) {
                const float4* wp = (const float4*)&w_lds[((c << 6) + (ky << 3) + kx) << 4];
                float4 w0 = wp[0], w1 = wp[1], w2 = wp[2], w3 = wp[3];
                float wv[16] = {w0.x, w0.y, w0.z, w0.w, w1.x, w1.y, w1.z, w1.w,
                                w2.x, w2.y, w2.z, w2.w, w3.x, w3.y, w3.z, w3.w};
#pragma unroll
                for (int co = 0; co < 16; ++co) {
                    acc[0][co] += in[kx] * wv[co];
                    acc[1][co] += in[4 + kx] * wv[co];
                }
            }
        }
    }
    const float s = 1.f / 255.f;
#pragma unroll
    for (int co = 0; co < 16; ++co) {
        float b = B[cg * 16 + co];
        float r0 = acc[0][co] * s + b; r0 = r0 > 0.f ? r0 : 0.f;
        float r1 = acc[1][co] * s + b; r1 = r1 > 0.f ? r1 : 0.f;
        *(float2*)&out[((im * 32 + cg * 16 + co) * 20 + oy) * 20 + ox0] = make_float2(r0, r1);
    }
}

// ---------------- conv2: (1024,32,20,20) -> (1024,64,9,9), k4 s2, relu ----------------
// Weights in LDS [ci][ky][kx][co16]; thread = 2 flattened pixels x 16 channels; grid.y = channel group (4).
__global__ __launch_bounds__(256) void k_conv2(const float* __restrict__ in,
                                               const float* __restrict__ W,
                                               const float* __restrict__ B,
                                               float* __restrict__ out) {
    __shared__ __align__(16) float w_lds[8192];           // 32 KB
    int cg = blockIdx.y;                                  // 0..3
#pragma unroll
    for (int l = threadIdx.x; l < 8192; l += 256) {
        int co = l & 15, r = l >> 4;                      // r = (ci*4+ky)*4+kx
        int kx = r & 3, ky = (r >> 2) & 3, ci = r >> 4;
        w_lds[l] = W[(((cg * 16 + co) * 32 + ci) * 4 + ky) * 4 + kx];
    }
    __syncthreads();
    int g = blockIdx.x * 256 + threadIdx.x;               // 0..41983
    int im = g / 41;
    int sl = g - im * 41;
    int p0 = sl * 2;
    int p1 = p0 + 1 > 80 ? 80 : p0 + 1;                   // clamp (same-addr rewrite is benign within thread)
    int oy0 = p0 / 9, ox0 = p0 - oy0 * 9;
    int oy1 = p1 / 9, ox1 = p1 - oy1 * 9;
    float acc[2][16];
#pragma unroll
    for (int p = 0; p < 2; ++p)
#pragma unroll
        for (int i = 0; i < 16; ++i) acc[p][i] = 0.f;
    const float* ib = in + im * 12800;
    for (int ci = 0; ci < 32; ++ci) {
#pragma unroll
        for (int ky = 0; ky < 4; ++ky) {
            const float* r0 = ib + (ci * 20 + oy0 * 2 + ky) * 20 + ox0 * 2;
            const float* r1 = ib + (ci * 20 + oy1 * 2 + ky) * 20 + ox1 * 2;
            float2 a0 = *(const float2*)(r0), a1 = *(const float2*)(r0 + 2);
            float2 b0 = *(const float2*)(r1), b1 = *(const float2*)(r1 + 2);
            float i0[4] = {a0.x, a0.y, a1.x, a1.y};
            float i1[4] = {b0.x, b0.y, b1.x, b1.y};
#pragma unroll
            for (int kx = 0; kx < 4; ++kx) {
                const float4* wp = (const float4*)&w_lds[(((ci << 2) + ky) * 4 + kx) << 4];
                float4 w0 = wp[0], w1 = wp[1], w2 = wp[2], w3 = wp[3];
                float wv[16] = {w0.x, w0.y, w0.z, w0.w, w1.x, w1.y, w1.z, w1.w,
                                w2.x, w2.y, w2.z, w2.w, w3.x, w3.y, w3.z, w3.w};
#pragma unroll
                for (int co = 0; co < 16; ++co) {
                    acc[0][co] += i0[kx] * wv[co];
                    acc[1][co] += i1[kx] * wv[co];
                }
            }
        }
    }
#pragma unroll
    for (int co = 0; co < 16; ++co) {
        float b = B[cg * 16 + co];
        float r0 = acc[0][co] + b; r0 = r0 > 0.f ? r0 : 0.f;
        float r1 = acc[1][co] + b; r1 = r1 > 0.f ? r1 : 0.f;
        out[((im * 64 + cg * 16 + co) * 9 + oy0) * 9 + ox0] = r0;
        out[((im * 64 + cg * 16 + co) * 9 + oy1) * 9 + ox1] = r1;
    }
}

// ---------------- conv3: (1024,64,9,9) -> (1024,64,7,7) flat, k3 s1, relu ----------------
// Weights in LDS [ci][ky][kx][co8]; thread = 2 flattened pixels x 8 channels; grid.y = channel group (8).
__global__ __launch_bounds__(256) void k_conv3(const float* __restrict__ in,
                                               const float* __restrict__ W,
                                               const float* __restrict__ B,
                                               float* __restrict__ out) {
    __shared__ __align__(16) float w_lds[4608];           // 18 KB
    int cg = blockIdx.y;                                  // 0..7
    for (int l = threadIdx.x; l < 4608; l += 256) {
        int co = l & 7, r = l >> 3;                       // r = (ci*3+ky)*3+kx
        int kx = r % 3, t = r / 3;
        int ky = t % 3, ci = t / 3;
        w_lds[l] = W[(((cg * 8 + co) * 64 + ci) * 3 + ky) * 3 + kx];
    }
    __syncthreads();
    int g = blockIdx.x * 256 + threadIdx.x;               // 0..25599
    int im = g / 25;
    int sl = g - im * 25;
    int p0 = sl * 2;
    int p1 = p0 + 1 > 48 ? 48 : p0 + 1;
    int oy0 = p0 / 7, ox0 = p0 - oy0 * 7;
    int oy1 = p1 / 7, ox1 = p1 - oy1 * 7;
    float acc[2][8];
#pragma unroll
    for (int p = 0; p < 2; ++p)
#pragma unroll
        for (int i = 0; i < 8; ++i) acc[p][i] = 0.f;
    const float* ib = in + im * 5184;
    for (int ci = 0; ci < 64; ++ci) {
#pragma unroll
        for (int ky = 0; ky < 3; ++ky) {
            const float* r0 = ib + ci * 81 + (oy0 + ky) * 9 + ox0;
            const float* r1 = ib + ci * 81 + (oy1 + ky) * 9 + ox1;
            float i0[3] = {r0[0], r0[1], r0[2]};
            float i1[3] = {r1[0], r1[1], r1[2]};
#pragma unroll
            for (int kx = 0; kx < 3; ++kx) {
                const float4* wp = (const float4*)&w_lds[(((ci * 3 + ky) * 3) + kx) << 3];
                float4 w0 = wp[0], w1 = wp[1];
                float wv[8] = {w0.x, w0.y, w0.z, w0.w, w1.x, w1.y, w1.z, w1.w};
#pragma unroll
                for (int co = 0; co < 8; ++co) {
                    acc[0][co] += i0[kx] * wv[co];
                    acc[1][co] += i1[kx] * wv[co];
                }
            }
        }
    }
#pragma unroll
    for (int co = 0; co < 8; ++co) {
        float b = B[cg * 8 + co];
        float r0 = acc[0][co] + b; r0 = r0 > 0.f ? r0 : 0.f;
        float r1 = acc[1][co] + b; r1 = r1 > 0.f ? r1 : 0.f;
        out[im * 3136 + (cg * 8 + co) * 49 + p0] = r0;     // flatten: ch*49 + pix
        out[im * 3136 + (cg * 8 + co) * 49 + p1] = r1;
    }
}

// ---------------- FC: feat = relu(a3[1024,3136] @ Wfc^T[3136,512] + bfc) ----------------
__global__ __launch_bounds__(256) void k_fc(const float* __restrict__ X,
                                            const float* __restrict__ W,
                                            const float* __restrict__ B,
                                            float* __restrict__ out) {
    int lane = threadIdx.x & 63;
    int wv = threadIdx.x >> 6;
    int m0 = blockIdx.x * 8;
    int n0 = blockIdx.y * 32 + wv * 8;
    float acc[64];
#pragma unroll
    for (int i = 0; i < 64; ++i) acc[i] = 0.f;
    for (int kk = 0; kk < 49; ++kk) {
        int k = kk * 64 + lane;
        float xv[8], wvv[8];
#pragma unroll
        for (int i = 0; i < 8; ++i) xv[i] = X[(m0 + i) * 3136 + k];
#pragma unroll
        for (int i = 0; i < 8; ++i) wvv[i] = W[(n0 + i) * 3136 + k];
#pragma unroll
        for (int mi = 0; mi < 8; ++mi)
#pragma unroll
            for (int ni = 0; ni < 8; ++ni)
                acc[mi * 8 + ni] += xv[mi] * wvv[ni];
    }
    float r = 0.f;
#pragma unroll
    for (int i = 0; i < 64; ++i) {
        float s = acc[i];
        s += __shfl_xor(s, 1); s += __shfl_xor(s, 2); s += __shfl_xor(s, 4);
        s += __shfl_xor(s, 8); s += __shfl_xor(s, 16); s += __shfl_xor(s, 32);
        if (lane == i) r = s;
    }
    int mi = lane >> 3, ni = lane & 7;
    float v = r + B[n0 + ni];
    out[(m0 + mi) * 512 + (n0 + ni)] = v > 0.f ? v : 0.f;
}

// ---------------- gx = feat @ W_ih[:, :512]^T + W_ih[:,512+act] + b_ih + b_hh ----------------
__global__ __launch_bounds__(256) void k_gx(const float* __restrict__ X,   // feat 1024x512
                                            const float* __restrict__ Wih, // 1024x517
                                            const float* __restrict__ bih,
                                            const float* __restrict__ bhh,
                                            const int* __restrict__ act,
                                            float* __restrict__ out) {
    int lane = threadIdx.x & 63;
    int wv = threadIdx.x >> 6;
    int m0 = blockIdx.x * 8;
    int n0 = blockIdx.y * 32 + wv * 8;
    float acc[64];
#pragma unroll
    for (int i = 0; i < 64; ++i) acc[i] = 0.f;
    for (int kk = 0; kk < 8; ++kk) {
        int k = kk * 64 + lane;
        float xv[8], wvv[8];
#pragma unroll
        for (int i = 0; i < 8; ++i) xv[i] = X[(m0 + i) * 512 + k];
#pragma unroll
        for (int i = 0; i < 8; ++i) wvv[i] = Wih[(n0 + i) * 517 + k];
#pragma unroll
        for (int mi = 0; mi < 8; ++mi)
#pragma unroll
            for (int ni = 0; ni < 8; ++ni)
                acc[mi * 8 + ni] += xv[mi] * wvv[ni];
    }
    float r = 0.f;
#pragma unroll
    for (int i = 0; i < 64; ++i) {
        float s = acc[i];
        s += __shfl_xor(s, 1); s += __shfl_xor(s, 2); s += __shfl_xor(s, 4);
        s += __shfl_xor(s, 8); s += __shfl_xor(s, 16); s += __shfl_xor(s, 32);
        if (lane == i) r = s;
    }
    int mi = lane >> 3, ni = lane & 7;
    int m = m0 + mi, n = n0 + ni;
    int a = act[m];
    float v = r + Wih[n * 517 + 512 + a] + bih[n] + bhh[n];
    out[m * 1024 + n] = v;
}

// ---------------- one LSTM step: g = gx[t] + (h*mask) @ Whh^T ; gates ; write c,h ----------------
__global__ __launch_bounds__(256) void k_lstm_step(int t,
                                                   const float* __restrict__ hsrc,
                                                   const float* __restrict__ csrc,
                                                   float* __restrict__ cdst,
                                                   const float* __restrict__ gx,
                                                   const float* __restrict__ Whh, // 1024x256
                                                   const float* __restrict__ done,
                                                   float* __restrict__ hs) {
    int lane = threadIdx.x & 63;
    int Wv = (blockIdx.x * 256 + threadIdx.x) >> 6;   // 0..2047
    int bp = Wv >> 7;                                  // 0..15
    int np = Wv & 127;                                 // 0..127
    int b0 = bp * 2, n0 = np * 2;
    float mb0 = 1.f - done[t * 32 + b0];
    float mb1 = 1.f - done[t * 32 + b0 + 1];
    float acc[16];
#pragma unroll
    for (int i = 0; i < 16; ++i) acc[i] = 0.f;
#pragma unroll
    for (int it = 0; it < 4; ++it) {
        int k = it * 64 + lane;
        float h0v = hsrc[b0 * 256 + k] * mb0;
        float h1v = hsrc[(b0 + 1) * 256 + k] * mb1;
#pragma unroll
        for (int p = 0; p < 2; ++p) {
#pragma unroll
            for (int g2 = 0; g2 < 4; ++g2) {
                float wv = Whh[(g2 * 256 + n0 + p) * 256 + k];
                acc[(0 * 2 + p) * 4 + g2] += h0v * wv;
                acc[(1 * 2 + p) * 4 + g2] += h1v * wv;
            }
        }
    }
    float gate[4] = {0.f, 0.f, 0.f, 0.f};
#pragma unroll
    for (int bi = 0; bi < 2; ++bi) {
#pragma unroll
        for (int p = 0; p < 2; ++p) {
#pragma unroll
            for (int g2 = 0; g2 < 4; ++g2) {
                float s = acc[(bi * 2 + p) * 4 + g2];
                s += __shfl_xor(s, 1); s += __shfl_xor(s, 2); s += __shfl_xor(s, 4);
                s += __shfl_xor(s, 8); s += __shfl_xor(s, 16); s += __shfl_xor(s, 32);
                if ((lane & 3) == bi * 2 + p) gate[g2] = s;
            }
        }
    }
    if (lane < 4) {
        int bi = lane >> 1, p = lane & 1;
        int b = b0 + bi, n = n0 + p;
        int row = t * 32 + b;
        float gi = gate[0] + gx[row * 1024 + 0 * 256 + n];
        float gf = gate[1] + gx[row * 1024 + 1 * 256 + n];
        float gg = gate[2] + gx[row * 1024 + 2 * 256 + n];
        float go = gate[3] + gx[row * 1024 + 3 * 256 + n];
        float mb = bi ? mb1 : mb0;
        float cm = csrc[b * 256 + n] * mb;
        float cn = sigm(gf) * cm + sigm(gi) * tanhf(gg);
        float hn = sigm(go) * tanhf(cn);
        cdst[b * 256 + n] = cn;
        hs[t * 8192 + b * 256 + n] = hn;
    }
}

// ---------------- heads: logits = tanh(h@Wp1^T+bp1)@Wp2^T+bp2 ; v similarly ; copy hT,cT ----------------
__global__ __launch_bounds__(256) void k_heads(const float* __restrict__ hs,
                                               const float* __restrict__ cb,
                                               const float* __restrict__ Wp1, const float* __restrict__ bp1,
                                               const float* __restrict__ Wp2, const float* __restrict__ bp2,
                                               const float* __restrict__ Wv1, const float* __restrict__ bv1,
                                               const float* __restrict__ Wv2, const float* __restrict__ bv2,
                                               float* __restrict__ out) {
    int lane = threadIdx.x & 63;
    int m = blockIdx.x * 4 + (threadIdx.x >> 6);   // 0..1023
    const float4* hv = (const float4*)(hs + m * 256);
    const float4* wp = (const float4*)(Wp1 + lane * 256);
    const float4* wq = (const float4*)(Wv1 + lane * 256);
    float ap = 0.f, av = 0.f;
#pragma unroll 8
    for (int k = 0; k < 64; ++k) {
        float4 h4 = hv[k];
        float4 p4 = wp[k];
        float4 q4 = wq[k];
        ap += h4.x * p4.x + h4.y * p4.y + h4.z * p4.z + h4.w * p4.w;
        av += h4.x * q4.x + h4.y * q4.y + h4.z * q4.z + h4.w * q4.w;
    }
    float hp = tanhf(ap + bp1[lane]);
    float hq = tanhf(av + bv1[lane]);
#pragma unroll
    for (int j = 0; j < 5; ++j) {
        float s = hp * Wp2[j * 64 + lane];
        s += __shfl_xor(s, 1); s += __shfl_xor(s, 2); s += __shfl_xor(s, 4);
        s += __shfl_xor(s, 8); s += __shfl_xor(s, 16); s += __shfl_xor(s, 32);
        if (lane == 0) out[m * 5 + j] = s + bp2[j];
    }
    float s = hq * Wv2[lane];
    s += __shfl_xor(s, 1); s += __shfl_xor(s, 2); s += __shfl_xor(s, 4);
    s += __shfl_xor(s, 8); s += __shfl_xor(s, 16); s += __shfl_xor(s, 32);
    if (lane == 0) out[5120 + m] = s + bv2[0];

    int g = blockIdx.x * 256 + threadIdx.x;
    if (g < 8192) {
        out[6144 + g] = hs[31 * 8192 + g];          // hT
        out[6144 + 8192 + g] = cb[g];               // cT
    }
}

extern "C" void kernel_launch(void* const* d_in, const int* in_sizes, int n_in,
                              void* d_out, int out_size, void* d_ws, size_t ws_size,
                              hipStream_t stream) {
    const float* image = (const float*)d_in[0];
    const int*   act   = (const int*)d_in[1];
    const float* done  = (const float*)d_in[2];
    const float* h0    = (const float*)d_in[3];
    const float* c0    = (const float*)d_in[4];
    const float* W1    = (const float*)d_in[5];
    const float* b1    = (const float*)d_in[6];
    const float* W2    = (const float*)d_in[7];
    const float* b2    = (const float*)d_in[8];
    const float* W3    = (const float*)d_in[9];
    const float* b3    = (const float*)d_in[10];
    const float* Wfc   = (const float*)d_in[11];
    const float* bfc   = (const float*)d_in[12];
    const float* Wih   = (const float*)d_in[13];
    const float* Whh   = (const float*)d_in[14];
    const float* bih   = (const float*)d_in[15];
    const float* bhh   = (const float*)d_in[16];
    const float* Wp1   = (const float*)d_in[17];
    const float* bp1   = (const float*)d_in[18];
    const float* Wp2   = (const float*)d_in[19];
    const float* bp2   = (const float*)d_in[20];
    const float* Wv1   = (const float*)d_in[21];
    const float* bv1   = (const float*)d_in[22];
    const float* Wv2   = (const float*)d_in[23];
    const float* bv2   = (const float*)d_in[24];
    float* out = (float*)d_out;
    float* ws = (float*)d_ws;

    // workspace layout (floats); a3/feat/gx/hs/c_buf overlap dead a1
    float* a2   = ws;                    // 5,308,416
    float* a1   = ws + 5308416;          // 13,107,200
    float* a3   = ws + 5308416;          // 3,211,264 (reuses a1 after conv2)
    float* feat = ws + 8519680;          // 524,288
    float* gx   = ws + 9043968;          // 1,048,576
    float* hs   = ws + 10092544;         // 262,144
    float* cb   = ws + 10354688;         // 8,192

    k_conv1<<<dim3(800, 2), 256, 0, stream>>>(image, W1, b1, a1);
    k_conv2<<<dim3(164, 4), 256, 0, stream>>>(a1, W2, b2, a2);
    k_conv3<<<dim3(100, 8), 256, 0, stream>>>(a2, W3, b3, a3);
    k_fc<<<dim3(128, 16), 256, 0, stream>>>(a3, Wfc, bfc, feat);
    k_gx<<<dim3(128, 32), 256, 0, stream>>>(feat, Wih, bih, bhh, act, gx);
    for (int t = 0; t < 32; ++t) {
        const float* hsrc = (t == 0) ? h0 : (hs + (t - 1) * 8192);
        const float* csrc = (t == 0) ? c0 : cb;
        k_lstm_step<<<512, 256, 0, stream>>>(t, hsrc, csrc, cb, gx, Whh, done, hs);
    }
    k_heads<<<256, 256, 0, stream>>>(hs, cb, Wp1, bp1, Wp2, bp2, Wv1, bv1, Wv2, bv2, out);
}

// Round 4
// 606.794 us; speedup vs baseline: 2.1130x; 1.3051x over previous
//
#include <hip/hip_runtime.h>
#include <math.h>

typedef float  f4v __attribute__((ext_vector_type(4)));
typedef short  s8v __attribute__((ext_vector_type(8)));

__device__ __forceinline__ float sigm(float x) { return 1.f / (1.f + expf(-x)); }
__device__ __forceinline__ unsigned short f2bf(float f) {
    unsigned int u = __float_as_uint(f);
    return (unsigned short)((u + 0x7FFF + ((u >> 16) & 1)) >> 16);   // RTNE
}

// ---------------- prep: pack weights to bf16 [N][K] layouts ----------------
// W2p[64][512] (natural OIHW flat). W3p[64][64][16] (3x3 padded to 16 slots ky*4+kx, zeros).
// Wfcp[512][3136] natural. Wihp[1024][512] (first 512 cols of [1024][517]).
__global__ __launch_bounds__(256) void k_prep(const float* __restrict__ W2, const float* __restrict__ W3,
                                              const float* __restrict__ Wfc, const float* __restrict__ Wih,
                                              unsigned short* __restrict__ W2p, unsigned short* __restrict__ W3p,
                                              unsigned short* __restrict__ Wfcp, unsigned short* __restrict__ Wihp) {
    int i = blockIdx.x * 256 + threadIdx.x;
    if (i < 32768) {
        W2p[i] = f2bf(W2[i]);
    } else if (i < 98304) {
        int j = i - 32768;
        int co = j >> 10, r = j & 1023, ci = r >> 4, s = r & 15, ky = s >> 2, kx = s & 3;
        W3p[j] = (ky < 3 && kx < 3) ? f2bf(W3[((co * 64 + ci) * 3 + ky) * 3 + kx]) : (unsigned short)0;
    } else if (i < 1703936) {
        int j = i - 98304;
        Wfcp[j] = f2bf(Wfc[j]);
    } else if (i < 2228224) {
        int j = i - 1703936;
        int n = j >> 9, k = j & 511;
        Wihp[j] = f2bf(Wih[n * 517 + k]);
    }
}

// ---------------- conv1: fp32 compute (weights via LDS broadcast), bf16 output ----------------
__global__ __launch_bounds__(256) void k_conv1(const float* __restrict__ img,
                                               const float* __restrict__ W,
                                               const float* __restrict__ B,
                                               unsigned short* __restrict__ out) {
    __shared__ __align__(16) float w_lds[3072];
    int cg = blockIdx.y;                                  // 0..1
#pragma unroll
    for (int l = threadIdx.x; l < 3072; l += 256) {
        int co = l & 15, r = l >> 4;
        w_lds[l] = W[((cg * 16 + co) * 3 + (r >> 6)) * 64 + (r & 63)];
    }
    __syncthreads();
    int g = blockIdx.x * 256 + threadIdx.x;               // 0..204799
    int im = g / 200;
    int pr = g - im * 200;
    int oy = pr / 10, ox0 = (pr - oy * 10) * 2;
    float acc[2][16];
#pragma unroll
    for (int p = 0; p < 2; ++p)
#pragma unroll
        for (int i = 0; i < 16; ++i) acc[p][i] = 0.f;
    const float* ibase = img + im * 21168;
#pragma unroll
    for (int c = 0; c < 3; ++c) {
#pragma unroll
        for (int ky = 0; ky < 8; ++ky) {
            const float* row = ibase + (c * 84 + oy * 4 + ky) * 84 + ox0 * 4;
            float4 v0 = *(const float4*)(row);
            float4 v1 = *(const float4*)(row + 4);
            float4 v2 = *(const float4*)(row + 8);
            float in[12] = {v0.x, v0.y, v0.z, v0.w, v1.x, v1.y, v1.z, v1.w, v2.x, v2.y, v2.z, v2.w};
#pragma unroll
            for (int kx = 0; kx < 8; ++kx) {
                const float4* wp = (const float4*)&w_lds[((c << 6) + (ky << 3) + kx) << 4];
                float4 w0 = wp[0], w1 = wp[1], w2 = wp[2], w3 = wp[3];
                float wv[16] = {w0.x, w0.y, w0.z, w0.w, w1.x, w1.y, w1.z, w1.w,
                                w2.x, w2.y, w2.z, w2.w, w3.x, w3.y, w3.z, w3.w};
#pragma unroll
                for (int co = 0; co < 16; ++co) {
                    acc[0][co] += in[kx] * wv[co];
                    acc[1][co] += in[4 + kx] * wv[co];
                }
            }
        }
    }
    const float s = 1.f / 255.f;
#pragma unroll
    for (int co = 0; co < 16; ++co) {
        float b = B[cg * 16 + co];
        float r0 = acc[0][co] * s + b; r0 = r0 > 0.f ? r0 : 0.f;
        float r1 = acc[1][co] * s + b; r1 = r1 > 0.f ? r1 : 0.f;
        ushort2 o; o.x = f2bf(r0); o.y = f2bf(r1);
        *(ushort2*)&out[((im * 32 + cg * 16 + co) * 20 + oy) * 20 + ox0] = o;
    }
}

// ---------------- conv2 (MFMA): M=82944 pixels, N=64, K=512 (ci*16+ky*4+kx) ----------------
// A = a1 bf16 (im,32,20,20), implicit im2col. Block=4 waves x 32m, wave tile 32m x 64n.
__global__ __launch_bounds__(256) void k_conv2(const unsigned short* __restrict__ A,
                                               const unsigned short* __restrict__ Bw,
                                               const float* __restrict__ bias,
                                               unsigned short* __restrict__ out) {
    int lane = threadIdx.x & 63, w = threadIdx.x >> 6;
    int l15 = lane & 15, q = lane >> 4;
    int m0 = blockIdx.x * 128 + w * 32;
    int ma = m0 + l15, mb = ma + 16;
    int ia = ma / 81, pa = ma - ia * 81; int oya = pa / 9, oxa = pa - oya * 9;
    int ib = mb / 81, pb = mb - ib * 81; int oyb = pb / 9, oxb = pb - oyb * 9;
    const unsigned short* Aa = A + ia * 12800 + oya * 40 + oxa * 2 + (q & 1) * 40; // + ky0*20
    const unsigned short* Ab = A + ib * 12800 + oyb * 40 + oxb * 2 + (q & 1) * 40;
    int ci0 = q >> 1;
    const unsigned short* B0 = Bw + (l15) * 512 + q * 8;
    const unsigned short* B1 = Bw + (16 + l15) * 512 + q * 8;
    const unsigned short* B2 = Bw + (32 + l15) * 512 + q * 8;
    const unsigned short* B3 = Bw + (48 + l15) * 512 + q * 8;
    f4v acc[8];
#pragma unroll
    for (int i = 0; i < 8; ++i) acc[i] = (f4v){0.f, 0.f, 0.f, 0.f};
    for (int c = 0; c < 16; ++c) {
        int ci = 2 * c + ci0;
        const unsigned short* pa_ = Aa + ci * 400;
        const unsigned short* pb_ = Ab + ci * 400;
        union { unsigned int u[4]; s8v v; } ua, ub;
        ua.u[0] = *(const unsigned int*)(pa_);      ua.u[1] = *(const unsigned int*)(pa_ + 2);
        ua.u[2] = *(const unsigned int*)(pa_ + 20); ua.u[3] = *(const unsigned int*)(pa_ + 22);
        ub.u[0] = *(const unsigned int*)(pb_);      ub.u[1] = *(const unsigned int*)(pb_ + 2);
        ub.u[2] = *(const unsigned int*)(pb_ + 20); ub.u[3] = *(const unsigned int*)(pb_ + 22);
        s8v b0 = *(const s8v*)B0, b1 = *(const s8v*)B1, b2 = *(const s8v*)B2, b3 = *(const s8v*)B3;
        B0 += 32; B1 += 32; B2 += 32; B3 += 32;
        acc[0] = __builtin_amdgcn_mfma_f32_16x16x32_bf16(ua.v, b0, acc[0], 0, 0, 0);
        acc[1] = __builtin_amdgcn_mfma_f32_16x16x32_bf16(ua.v, b1, acc[1], 0, 0, 0);
        acc[2] = __builtin_amdgcn_mfma_f32_16x16x32_bf16(ua.v, b2, acc[2], 0, 0, 0);
        acc[3] = __builtin_amdgcn_mfma_f32_16x16x32_bf16(ua.v, b3, acc[3], 0, 0, 0);
        acc[4] = __builtin_amdgcn_mfma_f32_16x16x32_bf16(ub.v, b0, acc[4], 0, 0, 0);
        acc[5] = __builtin_amdgcn_mfma_f32_16x16x32_bf16(ub.v, b1, acc[5], 0, 0, 0);
        acc[6] = __builtin_amdgcn_mfma_f32_16x16x32_bf16(ub.v, b2, acc[6], 0, 0, 0);
        acc[7] = __builtin_amdgcn_mfma_f32_16x16x32_bf16(ub.v, b3, acc[7], 0, 0, 0);
    }
#pragma unroll
    for (int mf = 0; mf < 2; ++mf) {
        int mt = m0 + mf * 16 + q * 4;
#pragma unroll
        for (int r = 0; r < 4; ++r) {
            int m = mt + r; int im = m / 81, p = m - im * 81;
#pragma unroll
            for (int nf = 0; nf < 4; ++nf) {
                int n = nf * 16 + l15;
                float v = acc[mf * 4 + nf][r] + bias[n];
                out[im * 5184 + n * 81 + p] = f2bf(v > 0.f ? v : 0.f);
            }
        }
    }
}

// ---------------- conv3 (MFMA): M=50176, N=64, K=64ci*16slots (3x3 zero-padded) ----------------
__global__ __launch_bounds__(256) void k_conv3(const unsigned short* __restrict__ A,
                                               const unsigned short* __restrict__ Bw,
                                               const float* __restrict__ bias,
                                               unsigned short* __restrict__ out) {
    int lane = threadIdx.x & 63, w = threadIdx.x >> 6;
    int l15 = lane & 15, q = lane >> 4;
    int m0 = blockIdx.x * 128 + w * 32;
    int ma = m0 + l15, mb = ma + 16;
    int ia = ma / 49, pa = ma - ia * 49; int oya = pa / 7, oxa = pa - oya * 7;
    int ib = mb / 49, pb = mb - ib * 49; int oyb = pb / 7, oxb = pb - oyb * 7;
    int ky0 = (q & 1) * 2;
    int r0off = ky0 * 9;
    int r1off = (ky0 + 1 > 2 ? 2 : ky0 + 1) * 9;
    int zr = q & 1;                                        // row1 is ky=3 -> zero
    const unsigned short* Aa = A + ia * 5184 + oya * 9 + oxa;
    const unsigned short* Ab = A + ib * 5184 + oyb * 9 + oxb;
    int ci0 = q >> 1;
    const unsigned short* B0 = Bw + (l15) * 1024 + q * 8;
    const unsigned short* B1 = Bw + (16 + l15) * 1024 + q * 8;
    const unsigned short* B2 = Bw + (32 + l15) * 1024 + q * 8;
    const unsigned short* B3 = Bw + (48 + l15) * 1024 + q * 8;
    f4v acc[8];
#pragma unroll
    for (int i = 0; i < 8; ++i) acc[i] = (f4v){0.f, 0.f, 0.f, 0.f};
    for (int c = 0; c < 32; ++c) {
        int ci = 2 * c + ci0;
        const unsigned short* pa_ = Aa + ci * 81;
        const unsigned short* pb_ = Ab + ci * 81;
        s8v av, bv;
        av[0] = pa_[r0off]; av[1] = pa_[r0off + 1]; av[2] = pa_[r0off + 2]; av[3] = 0;
        av[4] = zr ? (short)0 : (short)pa_[r1off];
        av[5] = zr ? (short)0 : (short)pa_[r1off + 1];
        av[6] = zr ? (short)0 : (short)pa_[r1off + 2];
        av[7] = 0;
        bv[0] = pb_[r0off]; bv[1] = pb_[r0off + 1]; bv[2] = pb_[r0off + 2]; bv[3] = 0;
        bv[4] = zr ? (short)0 : (short)pb_[r1off];
        bv[5] = zr ? (short)0 : (short)pb_[r1off + 1];
        bv[6] = zr ? (short)0 : (short)pb_[r1off + 2];
        bv[7] = 0;
        s8v b0 = *(const s8v*)B0, b1 = *(const s8v*)B1, b2 = *(const s8v*)B2, b3 = *(const s8v*)B3;
        B0 += 32; B1 += 32; B2 += 32; B3 += 32;
        acc[0] = __builtin_amdgcn_mfma_f32_16x16x32_bf16(av, b0, acc[0], 0, 0, 0);
        acc[1] = __builtin_amdgcn_mfma_f32_16x16x32_bf16(av, b1, acc[1], 0, 0, 0);
        acc[2] = __builtin_amdgcn_mfma_f32_16x16x32_bf16(av, b2, acc[2], 0, 0, 0);
        acc[3] = __builtin_amdgcn_mfma_f32_16x16x32_bf16(av, b3, acc[3], 0, 0, 0);
        acc[4] = __builtin_amdgcn_mfma_f32_16x16x32_bf16(bv, b0, acc[4], 0, 0, 0);
        acc[5] = __builtin_amdgcn_mfma_f32_16x16x32_bf16(bv, b1, acc[5], 0, 0, 0);
        acc[6] = __builtin_amdgcn_mfma_f32_16x16x32_bf16(bv, b2, acc[6], 0, 0, 0);
        acc[7] = __builtin_amdgcn_mfma_f32_16x16x32_bf16(bv, b3, acc[7], 0, 0, 0);
    }
#pragma unroll
    for (int mf = 0; mf < 2; ++mf) {
        int mt = m0 + mf * 16 + q * 4;
#pragma unroll
        for (int r = 0; r < 4; ++r) {
            int m = mt + r; int im = m / 49, p = m - im * 49;
#pragma unroll
            for (int nf = 0; nf < 4; ++nf) {
                int n = nf * 16 + l15;
                float v = acc[mf * 4 + nf][r] + bias[n];
                out[im * 3136 + n * 49 + p] = f2bf(v > 0.f ? v : 0.f);  // flat [im][ch*49+pix]
            }
        }
    }
}

// ---------------- FC (MFMA): feat = relu(a3[1024,3136] @ Wfcp^T) + bfc, bf16 out ----------------
__global__ __launch_bounds__(256) void k_fc(const unsigned short* __restrict__ A,
                                            const unsigned short* __restrict__ Bw,
                                            const float* __restrict__ bias,
                                            unsigned short* __restrict__ out) {
    int lane = threadIdx.x & 63, w = threadIdx.x >> 6;
    int l15 = lane & 15, q = lane >> 4;
    int m0 = blockIdx.x * 32 + (w & 1) * 16;
    int n0 = blockIdx.y * 64 + (w >> 1) * 32;
    const unsigned short* Ap = A + (m0 + l15) * 3136 + q * 8;
    const unsigned short* B0 = Bw + (n0 + l15) * 3136 + q * 8;
    const unsigned short* B1 = B0 + 16 * 3136;
    f4v acc0 = (f4v){0.f, 0.f, 0.f, 0.f}, acc1 = (f4v){0.f, 0.f, 0.f, 0.f};
    for (int c = 0; c < 98; ++c) {
        s8v av = *(const s8v*)Ap;
        s8v b0 = *(const s8v*)B0;
        s8v b1 = *(const s8v*)B1;
        Ap += 32; B0 += 32; B1 += 32;
        acc0 = __builtin_amdgcn_mfma_f32_16x16x32_bf16(av, b0, acc0, 0, 0, 0);
        acc1 = __builtin_amdgcn_mfma_f32_16x16x32_bf16(av, b1, acc1, 0, 0, 0);
    }
    float bi0 = bias[n0 + l15], bi1 = bias[n0 + 16 + l15];
#pragma unroll
    for (int r = 0; r < 4; ++r) {
        int m = m0 + q * 4 + r;
        float v0 = acc0[r] + bi0; v0 = v0 > 0.f ? v0 : 0.f;
        float v1 = acc1[r] + bi1; v1 = v1 > 0.f ? v1 : 0.f;
        out[m * 512 + n0 + l15] = f2bf(v0);
        out[m * 512 + n0 + 16 + l15] = f2bf(v1);
    }
}

// ---------------- gx (MFMA): gx = feat @ Wihp^T + onehot-col + b_ih + b_hh (fp32 out) ----------------
__global__ __launch_bounds__(256) void k_gx(const unsigned short* __restrict__ A,
                                            const unsigned short* __restrict__ Bw,
                                            const float* __restrict__ Wih,
                                            const float* __restrict__ bih,
                                            const float* __restrict__ bhh,
                                            const int* __restrict__ act,
                                            float* __restrict__ out) {
    int lane = threadIdx.x & 63, w = threadIdx.x >> 6;
    int l15 = lane & 15, q = lane >> 4;
    int m0 = blockIdx.x * 32 + (w & 1) * 16;
    int n0 = blockIdx.y * 64 + (w >> 1) * 32;
    const unsigned short* Ap = A + (m0 + l15) * 512 + q * 8;
    const unsigned short* B0 = Bw + (n0 + l15) * 512 + q * 8;
    const unsigned short* B1 = B0 + 16 * 512;
    f4v acc0 = (f4v){0.f, 0.f, 0.f, 0.f}, acc1 = (f4v){0.f, 0.f, 0.f, 0.f};
    for (int c = 0; c < 16; ++c) {
        s8v av = *(const s8v*)Ap;
        s8v b0 = *(const s8v*)B0;
        s8v b1 = *(const s8v*)B1;
        Ap += 32; B0 += 32; B1 += 32;
        acc0 = __builtin_amdgcn_mfma_f32_16x16x32_bf16(av, b0, acc0, 0, 0, 0);
        acc1 = __builtin_amdgcn_mfma_f32_16x16x32_bf16(av, b1, acc1, 0, 0, 0);
    }
    int na = n0 + l15, nb = n0 + 16 + l15;
    float ca = bih[na] + bhh[na], cb_ = bih[nb] + bhh[nb];
#pragma unroll
    for (int r = 0; r < 4; ++r) {
        int m = m0 + q * 4 + r;
        int a = act[m];
        out[m * 1024 + na] = acc0[r] + Wih[na * 517 + 512 + a] + ca;
        out[m * 1024 + nb] = acc1[r] + Wih[nb * 517 + 512 + a] + cb_;
    }
}

// ---------------- one LSTM step (fp32, unchanged) ----------------
__global__ __launch_bounds__(256) void k_lstm_step(int t,
                                                   const float* __restrict__ hsrc,
                                                   const float* __restrict__ csrc,
                                                   float* __restrict__ cdst,
                                                   const float* __restrict__ gx,
                                                   const float* __restrict__ Whh,
                                                   const float* __restrict__ done,
                                                   float* __restrict__ hs) {
    int lane = threadIdx.x & 63;
    int Wv = (blockIdx.x * 256 + threadIdx.x) >> 6;   // 0..2047
    int bp = Wv >> 7;
    int np = Wv & 127;
    int b0 = bp * 2, n0 = np * 2;
    float mb0 = 1.f - done[t * 32 + b0];
    float mb1 = 1.f - done[t * 32 + b0 + 1];
    float acc[16];
#pragma unroll
    for (int i = 0; i < 16; ++i) acc[i] = 0.f;
#pragma unroll
    for (int it = 0; it < 4; ++it) {
        int k = it * 64 + lane;
        float h0v = hsrc[b0 * 256 + k] * mb0;
        float h1v = hsrc[(b0 + 1) * 256 + k] * mb1;
#pragma unroll
        for (int p = 0; p < 2; ++p) {
#pragma unroll
            for (int g2 = 0; g2 < 4; ++g2) {
                float wv = Whh[(g2 * 256 + n0 + p) * 256 + k];
                acc[(0 * 2 + p) * 4 + g2] += h0v * wv;
                acc[(1 * 2 + p) * 4 + g2] += h1v * wv;
            }
        }
    }
    float gate[4] = {0.f, 0.f, 0.f, 0.f};
#pragma unroll
    for (int bi = 0; bi < 2; ++bi) {
#pragma unroll
        for (int p = 0; p < 2; ++p) {
#pragma unroll
            for (int g2 = 0; g2 < 4; ++g2) {
                float s = acc[(bi * 2 + p) * 4 + g2];
                s += __shfl_xor(s, 1); s += __shfl_xor(s, 2); s += __shfl_xor(s, 4);
                s += __shfl_xor(s, 8); s += __shfl_xor(s, 16); s += __shfl_xor(s, 32);
                if ((lane & 3) == bi * 2 + p) gate[g2] = s;
            }
        }
    }
    if (lane < 4) {
        int bi = lane >> 1, p = lane & 1;
        int b = b0 + bi, n = n0 + p;
        int row = t * 32 + b;
        float gi = gate[0] + gx[row * 1024 + 0 * 256 + n];
        float gf = gate[1] + gx[row * 1024 + 1 * 256 + n];
        float gg = gate[2] + gx[row * 1024 + 2 * 256 + n];
        float go = gate[3] + gx[row * 1024 + 3 * 256 + n];
        float mb = bi ? mb1 : mb0;
        float cm = csrc[b * 256 + n] * mb;
        float cn = sigm(gf) * cm + sigm(gi) * tanhf(gg);
        float hn = sigm(go) * tanhf(cn);
        cdst[b * 256 + n] = cn;
        hs[t * 8192 + b * 256 + n] = hn;
    }
}

// ---------------- heads (fp32, unchanged) ----------------
__global__ __launch_bounds__(256) void k_heads(const float* __restrict__ hs,
                                               const float* __restrict__ cb,
                                               const float* __restrict__ Wp1, const float* __restrict__ bp1,
                                               const float* __restrict__ Wp2, const float* __restrict__ bp2,
                                               const float* __restrict__ Wv1, const float* __restrict__ bv1,
                                               const float* __restrict__ Wv2, const float* __restrict__ bv2,
                                               float* __restrict__ out) {
    int lane = threadIdx.x & 63;
    int m = blockIdx.x * 4 + (threadIdx.x >> 6);   // 0..1023
    const float4* hv = (const float4*)(hs + m * 256);
    const float4* wp = (const float4*)(Wp1 + lane * 256);
    const float4* wq = (const float4*)(Wv1 + lane * 256);
    float ap = 0.f, av = 0.f;
#pragma unroll 8
    for (int k = 0; k < 64; ++k) {
        float4 h4 = hv[k];
        float4 p4 = wp[k];
        float4 q4 = wq[k];
        ap += h4.x * p4.x + h4.y * p4.y + h4.z * p4.z + h4.w * p4.w;
        av += h4.x * q4.x + h4.y * q4.y + h4.z * q4.z + h4.w * q4.w;
    }
    float hp = tanhf(ap + bp1[lane]);
    float hq = tanhf(av + bv1[lane]);
#pragma unroll
    for (int j = 0; j < 5; ++j) {
        float s = hp * Wp2[j * 64 + lane];
        s += __shfl_xor(s, 1); s += __shfl_xor(s, 2); s += __shfl_xor(s, 4);
        s += __shfl_xor(s, 8); s += __shfl_xor(s, 16); s += __shfl_xor(s, 32);
        if (lane == 0) out[m * 5 + j] = s + bp2[j];
    }
    float s = hq * Wv2[lane];
    s += __shfl_xor(s, 1); s += __shfl_xor(s, 2); s += __shfl_xor(s, 4);
    s += __shfl_xor(s, 8); s += __shfl_xor(s, 16); s += __shfl_xor(s, 32);
    if (lane == 0) out[5120 + m] = s + bv2[0];

    int g = blockIdx.x * 256 + threadIdx.x;
    if (g < 8192) {
        out[6144 + g] = hs[31 * 8192 + g];          // hT
        out[6144 + 8192 + g] = cb[g];               // cT
    }
}

extern "C" void kernel_launch(void* const* d_in, const int* in_sizes, int n_in,
                              void* d_out, int out_size, void* d_ws, size_t ws_size,
                              hipStream_t stream) {
    const float* image = (const float*)d_in[0];
    const int*   act   = (const int*)d_in[1];
    const float* done  = (const float*)d_in[2];
    const float* h0    = (const float*)d_in[3];
    const float* c0    = (const float*)d_in[4];
    const float* W1    = (const float*)d_in[5];
    const float* b1    = (const float*)d_in[6];
    const float* W2    = (const float*)d_in[7];
    const float* b2    = (const float*)d_in[8];
    const float* W3    = (const float*)d_in[9];
    const float* b3    = (const float*)d_in[10];
    const float* Wfc   = (const float*)d_in[11];
    const float* bfc   = (const float*)d_in[12];
    const float* Wih   = (const float*)d_in[13];
    const float* Whh   = (const float*)d_in[14];
    const float* bih   = (const float*)d_in[15];
    const float* bhh   = (const float*)d_in[16];
    const float* Wp1   = (const float*)d_in[17];
    const float* bp1   = (const float*)d_in[18];
    const float* Wp2   = (const float*)d_in[19];
    const float* bp2   = (const float*)d_in[20];
    const float* Wv1   = (const float*)d_in[21];
    const float* bv1   = (const float*)d_in[22];
    const float* Wv2   = (const float*)d_in[23];
    const float* bv2   = (const float*)d_in[24];
    float* out = (float*)d_out;
    char* base = (char*)d_ws;

    // ---- workspace layout (bytes) ----
    // a1 bf16 (26,214,400 B) at 0; a2 bf16 (+pad) at 26,214,432; weight packs at 36,831,328.
    // After conv2, a1 region is reused: a3, feat, gx, hs, cb.  Total 41,287,776 B.
    unsigned short* a1   = (unsigned short*)(base);
    unsigned short* a2   = (unsigned short*)(base + 26214432);
    unsigned short* W2p  = (unsigned short*)(base + 36831328);
    unsigned short* W3p  = W2p + 32768;
    unsigned short* Wfcp = W2p + 98304;
    unsigned short* Wihp = W2p + 1703936;
    unsigned short* a3   = (unsigned short*)(base);            // overlays dead a1
    unsigned short* feat = (unsigned short*)(base + 6422528);
    float* gx = (float*)(base + 7471104);
    float* hs = (float*)(base + 11665408);
    float* cb = (float*)(base + 12713984);

    k_prep<<<8704, 256, 0, stream>>>(W2, W3, Wfc, Wih, W2p, W3p, Wfcp, Wihp);
    k_conv1<<<dim3(800, 2), 256, 0, stream>>>(image, W1, b1, a1);
    k_conv2<<<648, 256, 0, stream>>>(a1, W2p, b2, a2);
    k_conv3<<<392, 256, 0, stream>>>(a2, W3p, b3, a3);
    k_fc<<<dim3(32, 8), 256, 0, stream>>>(a3, Wfcp, bfc, feat);
    k_gx<<<dim3(32, 16), 256, 0, stream>>>(feat, Wihp, Wih, bih, bhh, act, gx);
    for (int t = 0; t < 32; ++t) {
        const float* hsrc = (t == 0) ? h0 : (hs + (t - 1) * 8192);
        const float* csrc = (t == 0) ? c0 : cb;
        k_lstm_step<<<512, 256, 0, stream>>>(t, hsrc, csrc, cb, gx, Whh, done, hs);
    }
    k_heads<<<256, 256, 0, stream>>>(hs, cb, Wp1, bp1, Wp2, bp2, Wv1, bv1, Wv2, bv2, out);
}